// Round 4
// baseline (87.946 us; speedup 1.0000x reference)
//
#include <hip/hip_runtime.h>

#define HF 64
#define WF 64
#define CCH 512

typedef float  f32x4 __attribute__((ext_vector_type(4)));

// f32 -> bf16 round-to-nearest-even
__device__ __forceinline__ unsigned short f32_to_bf16(float f) {
    unsigned int x = __float_as_uint(f);
    unsigned int r = (x + 0x7FFFu + ((x >> 16) & 1u)) >> 16;
    return (unsigned short)r;
}
__device__ __forceinline__ float bf16_to_f32(unsigned short u) {
    return __uint_as_float(((unsigned int)u) << 16);
}

// ---------------- transpose+convert NCHW f32 -> NHWC bf16 -------------------
__global__ __launch_bounds__(256) void nchw_to_nhwc_bf16(const float* __restrict__ src,
                                                         unsigned short* __restrict__ dst) {
    __shared__ float tile[32][33];
    const int hw0 = blockIdx.x * 32;
    const int c0  = blockIdx.y * 32;
    const int b   = blockIdx.z;
    const int tx  = threadIdx.x & 31;
    const int ty  = threadIdx.x >> 5;   // 0..7
    const float*    s = src + (size_t)b * CCH * (HF * WF);
    unsigned short* d = dst + (size_t)b * (HF * WF) * CCH;
#pragma unroll
    for (int i = 0; i < 32; i += 8)
        tile[ty + i][tx] = s[(size_t)(c0 + ty + i) * (HF * WF) + hw0 + tx];
    __syncthreads();
#pragma unroll
    for (int i = 0; i < 32; i += 8)
        d[(size_t)(hw0 + ty + i) * CCH + c0 + tx] = f32_to_bf16(tile[tx][ty + i]);
}

// ---------------- prepass: bin roi indices by batch (B==2) ------------------
// Single block. Output order within a list is non-deterministic (atomics) but
// out[k] depends only on roi k itself, so final output is deterministic.
__global__ __launch_bounds__(256) void build_lists(const float* __restrict__ rois,
                                                   int K, int* __restrict__ cnt,
                                                   int* __restrict__ lists) {
    if (threadIdx.x < 2) cnt[threadIdx.x] = 0;
    __syncthreads();
    for (int k = threadIdx.x; k < K; k += blockDim.x) {
        int b = (int)rois[5 * k];
        int p = atomicAdd(&cnt[b], 1);
        lists[b * K + p] = k;
    }
}

// ---------------- main RoIAlign+avg kernel (NHWC bf16 gather) ---------------
// One block = (roi k, channel chunk of 256). Thread = one channel.
// PARTITION: remap blocks so XCDs 0-3 handle batch-0 rois, XCDs 4-7 batch-1,
// keeping each XCD's gather footprint ~4.2 MB (~= its 4 MiB L2).
template <bool PARTITION>
__global__ __launch_bounds__(256) void roialign_bf16(const unsigned short* __restrict__ ft,
                                                     const float* __restrict__ rois,
                                                     float* __restrict__ out,
                                                     const int* __restrict__ cnt,
                                                     const int* __restrict__ lists,
                                                     int K) {
    __shared__ __align__(16) float sbuf[256 * 49];

    int k, chunk;
    if (PARTITION) {
        const int bb  = blockIdx.x;                 // 0..2K-1
        const int h   = (bb >> 2) & 1;              // xcd>>2: desired batch half
        const int s   = ((bb >> 3) << 2) | (bb & 3); // slot within half, 0..K-1
        const int nh2 = 2 * cnt[h];
        int bsel, item;
        if (s < nh2) { bsel = h;     item = s; }
        else         { bsel = 1 - h; item = K + (s - nh2); }
        k     = lists[bsel * K + (item >> 1)];
        chunk = item & 1;
    } else {
        k     = blockIdx.x >> 1;
        chunk = blockIdx.x & 1;
    }

    const int tid = threadIdx.x;
    const int c   = chunk * 256 + tid;

    const float* r = rois + (size_t)k * 5;
    const int   b  = (int)r[0];
    const float x1 = r[1] * 0.0625f;
    const float y1 = r[2] * 0.0625f;
    const float x2 = r[3] * 0.0625f;
    const float y2 = r[4] * 0.0625f;
    const float bin_h = fmaxf(y2 - y1, 0.0f) / 7.0f;
    const float bin_w = fmaxf(x2 - x1, 0.0f) / 7.0f;

    int   hi_[8]; float hr_[8]; float fvh[8];
    int   wi_[8]; float wr_[8]; float fvw[8];
#pragma unroll
    for (int i = 0; i < 8; ++i) {
        float h  = y1 + (float)i * bin_h;
        float hs = fminf(floorf(h), 62.0f);
        hr_[i]   = h - hs;
        hi_[i]   = (int)fminf(fmaxf(hs, 0.0f), 62.0f);
        fvh[i]   = (h >= 0.0f && h < 64.0f) ? 1.0f : 0.0f;
        float w  = x1 + (float)i * bin_w;
        float ws = fminf(floorf(w), 62.0f);
        wr_[i]   = w - ws;
        wi_[i]   = (int)fminf(fmaxf(ws, 0.0f), 62.0f);
        fvw[i]   = (w >= 0.0f && w < 64.0f) ? 1.0f : 0.0f;
    }

    float  prev[8];
    float* srow = sbuf + tid * 49;

#pragma unroll
    for (int i = 0; i < 8; ++i) {
        float cur[8];
#pragma unroll
        for (int j = 0; j < 8; ++j) {
            const unsigned int o00 =
                (unsigned int)(((b * HF + hi_[i]) * WF + wi_[j]) * CCH + c);
            const float v00 = bf16_to_f32(ft[o00]);
            const float v01 = bf16_to_f32(ft[o00 + CCH]);
            const float v10 = bf16_to_f32(ft[o00 + WF * CCH]);
            const float v11 = bf16_to_f32(ft[o00 + WF * CCH + CCH]);
            const float top = v00 + wr_[j] * (v01 - v00);
            const float bot = v10 + wr_[j] * (v11 - v10);
            const float v   = top + hr_[i] * (bot - top);
            cur[j] = v * (fvh[i] * fvw[j]);
        }
        if (i > 0) {
#pragma unroll
            for (int j = 0; j < 7; ++j)
                srow[(i - 1) * 7 + j] =
                    0.25f * (prev[j] + prev[j + 1] + cur[j] + cur[j + 1]);
        }
#pragma unroll
        for (int j = 0; j < 8; ++j) prev[j] = cur[j];
    }

    __syncthreads();

    // coalesced non-temporal writeout (output is write-once, never read:
    // keep it out of L2 so it doesn't evict the feature working set)
    float* obase = out + ((size_t)k * CCH + (size_t)chunk * 256) * 49;
    const f32x4* s4 = reinterpret_cast<const f32x4*>(sbuf);
    f32x4*       o4 = reinterpret_cast<f32x4*>(obase);
    for (int idx = tid; idx < 3136; idx += 256)
        __builtin_nontemporal_store(s4[idx], &o4[idx]);
}

// ---------------- fallback: direct NCHW f32 (if ws too small) ---------------
__global__ __launch_bounds__(256) void roialign_f32_nchw(const float* __restrict__ ft,
                                                         const float* __restrict__ rois,
                                                         float* __restrict__ out) {
    __shared__ __align__(16) float sbuf[256 * 49];
    const int blk   = blockIdx.x;
    const int k     = blk >> 1;
    const int chunk = blk & 1;
    const int tid   = threadIdx.x;
    const int c     = chunk * 256 + tid;

    const float* r = rois + (size_t)k * 5;
    const int   b  = (int)r[0];
    const float x1 = r[1] * 0.0625f;
    const float y1 = r[2] * 0.0625f;
    const float x2 = r[3] * 0.0625f;
    const float y2 = r[4] * 0.0625f;
    const float bin_h = fmaxf(y2 - y1, 0.0f) / 7.0f;
    const float bin_w = fmaxf(x2 - x1, 0.0f) / 7.0f;

    int hi_[8]; float hr_[8]; float fvh[8];
    int wi_[8]; float wr_[8]; float fvw[8];
#pragma unroll
    for (int i = 0; i < 8; ++i) {
        float h  = y1 + (float)i * bin_h;
        float hs = fminf(floorf(h), 62.0f);
        hr_[i] = h - hs;
        hi_[i] = (int)fminf(fmaxf(hs, 0.0f), 62.0f);
        fvh[i] = (h >= 0.0f && h < 64.0f) ? 1.0f : 0.0f;
        float w  = x1 + (float)i * bin_w;
        float ws = fminf(floorf(w), 62.0f);
        wr_[i] = w - ws;
        wi_[i] = (int)fminf(fmaxf(ws, 0.0f), 62.0f);
        fvw[i] = (w >= 0.0f && w < 64.0f) ? 1.0f : 0.0f;
    }

    float prev[8];
    float* srow = sbuf + tid * 49;
#pragma unroll
    for (int i = 0; i < 8; ++i) {
        float cur[8];
#pragma unroll
        for (int j = 0; j < 8; ++j) {
            size_t o00 = (size_t)(b * CCH + c) * (HF * WF) + hi_[i] * WF + wi_[j];
            const float v00 = ft[o00];
            const float v01 = ft[o00 + 1];
            const float v10 = ft[o00 + WF];
            const float v11 = ft[o00 + WF + 1];
            const float top = v00 + wr_[j] * (v01 - v00);
            const float bot = v10 + wr_[j] * (v11 - v10);
            const float v   = top + hr_[i] * (bot - top);
            cur[j] = v * (fvh[i] * fvw[j]);
        }
        if (i > 0) {
#pragma unroll
            for (int j = 0; j < 7; ++j)
                srow[(i - 1) * 7 + j] =
                    0.25f * (prev[j] + prev[j + 1] + cur[j] + cur[j + 1]);
        }
#pragma unroll
        for (int j = 0; j < 8; ++j) prev[j] = cur[j];
    }
    __syncthreads();
    float* obase = out + ((size_t)k * CCH + (size_t)chunk * 256) * 49;
    const f32x4* s4 = reinterpret_cast<const f32x4*>(sbuf);
    f32x4*       o4 = reinterpret_cast<f32x4*>(obase);
    for (int idx = tid; idx < 3136; idx += 256)
        __builtin_nontemporal_store(s4[idx], &o4[idx]);
}

extern "C" void kernel_launch(void* const* d_in, const int* in_sizes, int n_in,
                              void* d_out, int out_size, void* d_ws, size_t ws_size,
                              hipStream_t stream) {
    const float* feat = (const float*)d_in[0];
    const float* rois = (const float*)d_in[1];
    float*       out  = (float*)d_out;

    const int B = in_sizes[0] / (CCH * HF * WF);
    const int K = in_sizes[1] / 5;

    const size_t featBytes = (size_t)B * CCH * HF * WF * sizeof(unsigned short);
    // workspace layout: [features bf16][cnt:2 ints][lists:2K ints]
    const size_t metaBytes = (2 + 2 * (size_t)K) * sizeof(int);

    if (ws_size >= featBytes + metaBytes && B == 2) {
        unsigned short* ftr = (unsigned short*)d_ws;
        int* cnt   = (int*)((char*)d_ws + featBytes);
        int* lists = cnt + 2;
        dim3 tg((HF * WF) / 32, CCH / 32, B);
        nchw_to_nhwc_bf16<<<tg, 256, 0, stream>>>(feat, ftr);
        build_lists<<<1, 256, 0, stream>>>(rois, K, cnt, lists);
        roialign_bf16<true><<<K * 2, 256, 0, stream>>>(ftr, rois, out, cnt, lists, K);
    } else if (ws_size >= featBytes) {
        unsigned short* ftr = (unsigned short*)d_ws;
        dim3 tg((HF * WF) / 32, CCH / 32, B);
        nchw_to_nhwc_bf16<<<tg, 256, 0, stream>>>(feat, ftr);
        roialign_bf16<false><<<K * 2, 256, 0, stream>>>(ftr, rois, out, nullptr, nullptr, K);
    } else {
        roialign_f32_nchw<<<K * 2, 256, 0, stream>>>(feat, rois, out);
    }
}